// Round 10
// baseline (137.766 us; speedup 1.0000x reference)
//
#include <hip/hip_runtime.h>

// KANvolution: B=4, H=W=66, C=32, F=64, KH=KW=3, Ho=Wo=64, 17 control points.
// Spline = 2-point lerp (hat basis: exactly 2 nonzero weights summing to 1).
//
// d_ws layout:
//   Tsp: uint f16x2 pair (cp_eff[k], cp_eff[k+1]) at dword
//        W(f,cij,k) = (f>>5)*147456 + cij*512 + ((f&31)>>1)*32 + k*2 + (f&1)
//        -> inner ds_read_b64 pair at (cij*512 + f2*32 + 2k, +32): banks (2k,2k+1),
//           all 16 k disjoint bank pairs -> conflict-free for any k mix.
//   Tws: float w_silu in per-(fh,half,chunk,wave) quad-blocks of 36 dwords
//        (stride 40 for 16B alignment): Q = ((fh*2+h)*16+ch)*8 + wl;
//        Tws[Q*40 + cc*4 + fq] -> loaded wave-uniform (readfirstlane) = off LDS pipe.

#define NCIJ 288
// LDS dword offsets (1024-thread block, two c-half wave-groups)
#define SPL  0             // 2 x 4608 spline chunk              [0,9216)
#define XPW  9216          // 2 x 1280 xp records (tap-paired)   [9216,11776)
#define XSW  11776         // 32 x 100 x-tile                    [11776,14976)
#define TOTW 14976         // 59904 B -> 2 blocks/CU

typedef _Float16 half2_t  __attribute__((ext_vector_type(2)));
typedef __fp16   fp16x2_t __attribute__((ext_vector_type(2)));
union h2u { half2_t h; fp16x2_t f; uint u; };

// ---- build: one block per cij, 256 threads ----
__global__ __launch_bounds__(256)
void build_table(const float* __restrict__ cp, const float* __restrict__ wsp,
                 const float* __restrict__ wsl, uint* __restrict__ Tsp,
                 float* __restrict__ Tws) {
    __shared__ float L[64 * 19];
    __shared__ float Lw[64], Ls[64];
    int cij = blockIdx.x, t = threadIdx.x;
    for (int e = t; e < 64 * 17; e += 256) {
        int f = e / 17, g = e - f * 17;
        L[f * 19 + g] = cp[((size_t)f * NCIJ + cij) * 17 + g];
    }
    if (t < 64) {
        Lw[t] = wsl[t * NCIJ + cij];
        Ls[t] = wsp[t * NCIJ + cij];
    }
    __syncthreads();
    int f = t & 63;
    float s = Ls[f];
    int base = (f >> 5) * (NCIJ * 512) + cij * 512 + ((f & 31) >> 1) * 32 + (f & 1);
    #pragma unroll
    for (int kk = 0; kk < 4; ++kk) {
        int k = (t >> 6) * 4 + kk;
        h2u cv;
        cv.f = __builtin_amdgcn_cvt_pkrtz(s * L[f * 19 + k], s * L[f * 19 + k + 1]);
        Tsp[base + k * 2] = cv.u;
    }
    if (t < 64) {
        int fh = t >> 5, fl = t & 31, wl = fl >> 2, fq = fl & 3;
        int h = cij / 144, gl = cij - h * 144, ch2 = gl / 9, cc = gl - ch2 * 9;
        int Q = ((fh * 2 + h) * 16 + ch2) * 8 + wl;
        Tws[Q * 40 + cc * 4 + fq] = Lw[t];
    }
}

// ---- main: 512 blocks (256 tiles x 2 fh) x 1024 threads (16 waves) ----
// waves 0-7: channels 0-15 ; waves 8-15: channels 16-31 ; LDS reduction at end.
__global__ __launch_bounds__(1024, 8)
void kan_conv(const float* __restrict__ x, const uint* __restrict__ Tsp,
              const float* __restrict__ Tws, const float* __restrict__ bias,
              float* __restrict__ out) {
    __shared__ uint shm[TOTW];

    int tid = threadIdx.x;
    int lane = tid & 63, w = tid >> 6;
    int half = w >> 3;                     // c-half this wave accumulates
    int wl = w & 7;                        // wave index within half
    int q = wl << 2;                       // f-quarter within the 32-f half
    int ht = tid & 511;                    // thread index within half
    int dy = lane >> 3, dx = lane & 7;
    int bid = blockIdx.x;
    int tile = bid & 255;
    int fh = bid >> 8;
    int b = tile >> 6, ty = (tile >> 3) & 7, tx = tile & 7;
    int ho0 = ty << 3, wo0 = tx << 3;
    int cij0 = half * 144;                 // first cij of this half

    // stage x tile: 10x10 halo x all 32 channels, [c][r*10+col]
    for (int e = tid; e < 3200; e += 1024) {
        int c = e & 31, rc = e >> 5;
        int r = rc / 10, col = rc - r * 10;
        shm[XSW + c * 100 + rc] =
            __float_as_uint(x[(((b * 66) + ho0 + r) * 66 + (wo0 + col)) * 32 + c]);
    }

    float acc[4];
    #pragma unroll
    for (int ff = 0; ff < 4; ++ff)
        acc[ff] = (half == 0) ? bias[fh * 32 + q + ff] : 0.f;

    int hb  = half * 4608;                 // this half's spline buffer base
    int w64 = wl * 64;                     // f-pair base (dwords) for this wave
    int xpb = XPW + half * 1280;           // this half's xp base

    for (int ch = 0; ch < 16; ++ch) {      // local channel = chunk
        __syncthreads();                   // prev chunk's compute done (covers x tile)

        // w_silu quad-block: wave-uniform -> scalar/broadcast loads, off the LDS pipe
        int qb = __builtin_amdgcn_readfirstlane(
            ((((fh * 2 + half) * 16 + ch) * 8) + wl) * 40);
        const float* wsq = Tws + qb;
        float4 wv[9];
        #pragma unroll
        for (int cc = 0; cc < 9; ++cc) wv[cc] = *(const float4*)(wsq + cc * 4);

        // stage this half's spline chunk: 1152 uint4, dest contiguous
        {
            int cijc = fh * NCIJ + cij0 + ch * 9;
            const uint4* s1 = (const uint4*)(Tsp + (size_t)cijc * 512);
            uint4* d1 = (uint4*)&shm[hb];
            for (int e = ht; e < 1152; e += 512) d1[e] = s1[e];
        }
        // precompute xp records: 9 taps x 64 pixels, 8B, tap-PAIRED layout:
        // dword = (ij>>1)*256 + px*4 + (ij&1)*2  -> inner b128 reads 2 taps at once
        {
            int p = ht;
            #pragma unroll 1
            for (int rep = 0; rep < 2; ++rep) {
                if (p < 576) {
                    int ij = p >> 6, px = p & 63;
                    int i = ij / 3, j = ij - i * 3;
                    int pdy = px >> 3, pdx = px & 7;
                    float xv = __uint_as_float(
                        shm[XSW + (half * 16 + ch) * 100 + (pdy + i) * 10 + pdx + j]);
                    float xc = fminf(fmaxf(xv, -1.f), 1.f);
                    float u = fmaf(xc, 8.f, 8.f);
                    int k = (int)u; k = (k > 15) ? 15 : k;
                    float t = u - (float)k;
                    h2u at; at.f = __builtin_amdgcn_cvt_pkrtz(1.f - t, t);
                    float sl = xv * __builtin_amdgcn_rcpf(1.f + __expf(-xv));
                    uint su = (__float_as_uint(sl) & ~15u) | (uint)k;
                    uint2 rec; rec.x = at.u; rec.y = su;
                    *(uint2*)&shm[xpb + ((ij >> 1) << 8) + (px << 2) + ((ij & 1) << 1)] = rec;
                }
                p += 512;
            }
        }
        __syncthreads();                   // tab + xp ready

#if __has_builtin(__builtin_amdgcn_fdot2)
#define PROC(cc, atw, suw) { \
    uint su_ = (suw); int k2_ = (int)(su_ & 15u); \
    float sl_ = __uint_as_float(su_ & ~15u); \
    uint2 p0_ = *(const uint2*)&shm[hb + (cc) * 512 + w64 + (k2_ << 1)]; \
    uint2 p1_ = *(const uint2*)&shm[hb + (cc) * 512 + w64 + 32 + (k2_ << 1)]; \
    h2u at_; at_.u = (atw); \
    h2u c0_, c1_, c2_, c3_; \
    c0_.u = p0_.x; c1_.u = p0_.y; c2_.u = p1_.x; c3_.u = p1_.y; \
    acc[0] = __builtin_amdgcn_fdot2(at_.h, c0_.h, acc[0], false); \
    acc[1] = __builtin_amdgcn_fdot2(at_.h, c1_.h, acc[1], false); \
    acc[2] = __builtin_amdgcn_fdot2(at_.h, c2_.h, acc[2], false); \
    acc[3] = __builtin_amdgcn_fdot2(at_.h, c3_.h, acc[3], false); \
    acc[0] = fmaf(sl_, wv[cc].x, acc[0]); \
    acc[1] = fmaf(sl_, wv[cc].y, acc[1]); \
    acc[2] = fmaf(sl_, wv[cc].z, acc[2]); \
    acc[3] = fmaf(sl_, wv[cc].w, acc[3]); }
#else
#define PROC(cc, atw, suw) { \
    uint su_ = (suw); int k2_ = (int)(su_ & 15u); \
    float sl_ = __uint_as_float(su_ & ~15u); \
    uint2 p0_ = *(const uint2*)&shm[hb + (cc) * 512 + w64 + (k2_ << 1)]; \
    uint2 p1_ = *(const uint2*)&shm[hb + (cc) * 512 + w64 + 32 + (k2_ << 1)]; \
    h2u at_; at_.u = (atw); \
    float a0_ = (float)at_.h.x, a1_ = (float)at_.h.y; \
    uint prs_[4] = {p0_.x, p0_.y, p1_.x, p1_.y}; \
    _Pragma("unroll") \
    for (int ff = 0; ff < 4; ++ff) { \
        h2u cv_; cv_.u = prs_[ff]; \
        acc[ff] = fmaf(a0_, (float)cv_.h.x, fmaf(a1_, (float)cv_.h.y, acc[ff])); \
    } \
    acc[0] = fmaf(sl_, wv[cc].x, acc[0]); \
    acc[1] = fmaf(sl_, wv[cc].y, acc[1]); \
    acc[2] = fmaf(sl_, wv[cc].z, acc[2]); \
    acc[3] = fmaf(sl_, wv[cc].w, acc[3]); }
#endif

        #pragma unroll
        for (int ccp = 0; ccp < 4; ++ccp) {
            // paired xp read: 2 taps per b128, exactly 2 dwords/bank -> conflict-free
            uint4 rr = *(const uint4*)&shm[xpb + (ccp << 8) + (lane << 2)];
            PROC(2 * ccp,     rr.x, rr.y);
            PROC(2 * ccp + 1, rr.z, rr.w);
        }
        {
            uint2 r8 = *(const uint2*)&shm[xpb + 1024 + (lane << 2)];
            PROC(8, r8.x, r8.y);
        }
#undef PROC
    }

    // block-internal reduction: half 1 writes partials, half 0 adds + stores
    __syncthreads();
    if (half == 1) {
        uint4 pv;
        pv.x = __float_as_uint(acc[0]); pv.y = __float_as_uint(acc[1]);
        pv.z = __float_as_uint(acc[2]); pv.w = __float_as_uint(acc[3]);
        *(uint4*)&shm[wl * 256 + lane * 4] = pv;
    }
    __syncthreads();
    if (half == 0) {
        uint4 pv = *(const uint4*)&shm[wl * 256 + lane * 4];
        acc[0] += __uint_as_float(pv.x);
        acc[1] += __uint_as_float(pv.y);
        acc[2] += __uint_as_float(pv.z);
        acc[3] += __uint_as_float(pv.w);
        size_t base = ((((size_t)b * 64 + (ho0 + dy)) * 64 + (wo0 + dx)) * 64) + fh * 32 + q;
        *(float4*)(out + base) = make_float4(acc[0], acc[1], acc[2], acc[3]);
    }
}

extern "C" void kernel_launch(void* const* d_in, const int* in_sizes, int n_in,
                              void* d_out, int out_size, void* d_ws, size_t ws_size,
                              hipStream_t stream) {
    const float* x    = (const float*)d_in[0];
    const float* cp   = (const float*)d_in[1];
    const float* wsp  = (const float*)d_in[2];
    const float* wsl  = (const float*)d_in[3];
    const float* bias = (const float*)d_in[4];
    float* out = (float*)d_out;
    uint*  Tsp = (uint*)d_ws;                       // 294912 dwords
    float* Tws = (float*)d_ws + 294912;             // 512*40 = 20480 dwords

    hipLaunchKernelGGL(build_table, dim3(NCIJ), dim3(256), 0, stream,
                       cp, wsp, wsl, Tsp, Tws);
    hipLaunchKernelGGL(kan_conv, dim3(512), dim3(1024), 0, stream,
                       x, Tsp, Tws, bias, out);
}

// Round 11
// 122.014 us; speedup vs baseline: 1.1291x; 1.1291x over previous
//
#include <hip/hip_runtime.h>

// KANvolution: B=4, H=W=66, C=32, F=64, KH=KW=3, Ho=Wo=64, 17 control points.
// Spline = 2-point lerp (hat basis: exactly 2 nonzero weights summing to 1).
//
// d_ws layout:
//   Tsp: uint f16x2 pair (cp_eff[k], cp_eff[k+1]) at dword
//        W(f,cij,k) = (f>>5)*147456 + cij*512 + ((f&31)>>1)*32 + k*2 + (f&1)
//        -> inner ds_read_b64 pair at (cij*512 + f2*32 + 2k, +32): banks (2k,2k+1),
//           all 16 k disjoint bank pairs -> conflict-free for any k mix.
//   Tws: float w_silu in per-(fh,half,chunk,wave) quad-blocks of 36 dwords
//        (stride 40 for 16B alignment): Q = ((fh*2+h)*16+ch)*8 + wl;
//        Tws[Q*40 + cc*4 + fq] -> wave-uniform s_loads at chunk head = off LDS pipe.

#define NCIJ 288
// LDS dword offsets (1024-thread block, two c-half wave-groups)
#define SPL  0             // 2 x 4608 spline chunk              [0,9216)
#define XPW  9216          // 2 x 1152 xp records (R9 stride-2)  [9216,11520)
#define XSW  11520         // 32 x 100 x-tile                    [11520,14720)
#define TOTW 14720         // 58880 B -> 2 blocks/CU

typedef _Float16 half2_t  __attribute__((ext_vector_type(2)));
typedef __fp16   fp16x2_t __attribute__((ext_vector_type(2)));
union h2u { half2_t h; fp16x2_t f; uint u; };

// ---- build: one block per cij, 256 threads ----
__global__ __launch_bounds__(256)
void build_table(const float* __restrict__ cp, const float* __restrict__ wsp,
                 const float* __restrict__ wsl, uint* __restrict__ Tsp,
                 float* __restrict__ Tws) {
    __shared__ float L[64 * 19];
    __shared__ float Lw[64], Ls[64];
    int cij = blockIdx.x, t = threadIdx.x;
    for (int e = t; e < 64 * 17; e += 256) {
        int f = e / 17, g = e - f * 17;
        L[f * 19 + g] = cp[((size_t)f * NCIJ + cij) * 17 + g];
    }
    if (t < 64) {
        Lw[t] = wsl[t * NCIJ + cij];
        Ls[t] = wsp[t * NCIJ + cij];
    }
    __syncthreads();
    int f = t & 63;
    float s = Ls[f];
    int base = (f >> 5) * (NCIJ * 512) + cij * 512 + ((f & 31) >> 1) * 32 + (f & 1);
    #pragma unroll
    for (int kk = 0; kk < 4; ++kk) {
        int k = (t >> 6) * 4 + kk;
        h2u cv;
        cv.f = __builtin_amdgcn_cvt_pkrtz(s * L[f * 19 + k], s * L[f * 19 + k + 1]);
        Tsp[base + k * 2] = cv.u;
    }
    if (t < 64) {
        int fh = t >> 5, fl = t & 31, wl = fl >> 2, fq = fl & 3;
        int h = cij / 144, gl = cij - h * 144, ch2 = gl / 9, cc = gl - ch2 * 9;
        int Q = ((fh * 2 + h) * 16 + ch2) * 8 + wl;
        Tws[Q * 40 + cc * 4 + fq] = Lw[t];
    }
}

// ---- main: 512 blocks (256 tiles x 2 fh) x 1024 threads (16 waves) ----
// waves 0-7: channels 0-15 ; waves 8-15: channels 16-31 ; LDS reduction at end.
__global__ __launch_bounds__(1024, 8)
void kan_conv(const float* __restrict__ x, const uint* __restrict__ Tsp,
              const float* __restrict__ Tws, const float* __restrict__ bias,
              float* __restrict__ out) {
    __shared__ uint shm[TOTW];

    int tid = threadIdx.x;
    int lane = tid & 63, w = tid >> 6;
    int half = w >> 3;                     // c-half this wave accumulates
    int wl = w & 7;                        // wave index within half
    int q = wl << 2;                       // f-quarter within the 32-f half
    int ht = tid & 511;                    // thread index within half
    int dy = lane >> 3, dx = lane & 7;
    int bid = blockIdx.x;
    int tile = bid & 255;
    int fh = bid >> 8;
    int b = tile >> 6, ty = (tile >> 3) & 7, tx = tile & 7;
    int ho0 = ty << 3, wo0 = tx << 3;
    int cij0 = half * 144;                 // first cij of this half

    // stage x tile: 10x10 halo x all 32 channels, [c][r*10+col]
    for (int e = tid; e < 3200; e += 1024) {
        int c = e & 31, rc = e >> 5;
        int r = rc / 10, col = rc - r * 10;
        shm[XSW + c * 100 + rc] =
            __float_as_uint(x[(((b * 66) + ho0 + r) * 66 + (wo0 + col)) * 32 + c]);
    }

    float acc[4];
    #pragma unroll
    for (int ff = 0; ff < 4; ++ff)
        acc[ff] = (half == 0) ? bias[fh * 32 + q + ff] : 0.f;

    int hb  = half * 4608;                 // this half's spline buffer base
    int w64 = wl * 64;                     // f-pair base (dwords) for this wave

    for (int ch = 0; ch < 16; ++ch) {      // local channel = chunk
        __syncthreads();                   // prev chunk's compute done (covers x tile)

        // w_silu quad-block: wave-uniform -> s_loads into registers, off the LDS pipe.
        // Issued at chunk head; latency hidden behind staging + precompute + barrier.
        int qb = __builtin_amdgcn_readfirstlane(
            ((((fh * 2 + half) * 16 + ch) * 8) + wl) * 40);
        const float* wsq = Tws + qb;
        float4 wv[9];
        #pragma unroll
        for (int cc = 0; cc < 9; ++cc) wv[cc] = *(const float4*)(wsq + cc * 4);

        // stage this half's spline chunk: 1152 uint4, dest contiguous
        {
            int cijc = fh * NCIJ + cij0 + ch * 9;
            const uint4* s1 = (const uint4*)(Tsp + (size_t)cijc * 512);
            uint4* d1 = (uint4*)&shm[hb];
            for (int e = ht; e < 1152; e += 512) d1[e] = s1[e];
        }
        // precompute xp records: 9 taps x 64 pixels, 8B each, stride-2 (R9 layout)
        {
            int p = ht;
            #pragma unroll 1
            for (int rep = 0; rep < 2; ++rep) {
                if (p < 576) {
                    int ij = p >> 6, px = p & 63;
                    int i = ij / 3, j = ij - i * 3;
                    int pdy = px >> 3, pdx = px & 7;
                    float xv = __uint_as_float(
                        shm[XSW + (half * 16 + ch) * 100 + (pdy + i) * 10 + pdx + j]);
                    float xc = fminf(fmaxf(xv, -1.f), 1.f);
                    float u = fmaf(xc, 8.f, 8.f);
                    int k = (int)u; k = (k > 15) ? 15 : k;
                    float t = u - (float)k;
                    h2u at; at.f = __builtin_amdgcn_cvt_pkrtz(1.f - t, t);
                    float sl = xv * __builtin_amdgcn_rcpf(1.f + __expf(-xv));
                    uint su = (__float_as_uint(sl) & ~15u) | (uint)k;
                    uint2 rec; rec.x = at.u; rec.y = su;
                    *(uint2*)&shm[XPW + half * 1152 + p * 2] = rec;
                }
                p += 512;
            }
        }
        __syncthreads();                   // tab + xp ready

        #pragma unroll
        for (int cc = 0; cc < 9; ++cc) {
            uint2 r = *(const uint2*)&shm[XPW + half * 1152 + lane * 2 + cc * 128];
            uint su = r.y;
            int k2 = (int)(su & 15u);
            float sl = __uint_as_float(su & ~15u);
            // two b64 pair reads, banks (2k,2k+1): conflict-free for any k mix
            uint2 p0 = *(const uint2*)&shm[hb + cc * 512 + w64 + (k2 << 1)];
            uint2 p1 = *(const uint2*)&shm[hb + cc * 512 + w64 + 32 + (k2 << 1)];
#if __has_builtin(__builtin_amdgcn_fdot2)
            h2u at; at.u = r.x;
            h2u c0, c1, c2u, c3;
            c0.u = p0.x; c1.u = p0.y; c2u.u = p1.x; c3.u = p1.y;
            acc[0] = __builtin_amdgcn_fdot2(at.h, c0.h, acc[0], false);
            acc[1] = __builtin_amdgcn_fdot2(at.h, c1.h, acc[1], false);
            acc[2] = __builtin_amdgcn_fdot2(at.h, c2u.h, acc[2], false);
            acc[3] = __builtin_amdgcn_fdot2(at.h, c3.h, acc[3], false);
#else
            h2u atv; atv.u = r.x;
            float a0 = (float)atv.h.x, a1 = (float)atv.h.y;
            uint prs[4] = {p0.x, p0.y, p1.x, p1.y};
            #pragma unroll
            for (int ff = 0; ff < 4; ++ff) {
                h2u cv; cv.u = prs[ff];
                acc[ff] = fmaf(a0, (float)cv.h.x, fmaf(a1, (float)cv.h.y, acc[ff]));
            }
#endif
            acc[0] = fmaf(sl, wv[cc].x, acc[0]);
            acc[1] = fmaf(sl, wv[cc].y, acc[1]);
            acc[2] = fmaf(sl, wv[cc].z, acc[2]);
            acc[3] = fmaf(sl, wv[cc].w, acc[3]);
        }
    }

    // block-internal reduction: half 1 writes partials, half 0 adds + stores
    __syncthreads();
    if (half == 1) {
        uint4 pv;
        pv.x = __float_as_uint(acc[0]); pv.y = __float_as_uint(acc[1]);
        pv.z = __float_as_uint(acc[2]); pv.w = __float_as_uint(acc[3]);
        *(uint4*)&shm[wl * 256 + lane * 4] = pv;
    }
    __syncthreads();
    if (half == 0) {
        uint4 pv = *(const uint4*)&shm[wl * 256 + lane * 4];
        acc[0] += __uint_as_float(pv.x);
        acc[1] += __uint_as_float(pv.y);
        acc[2] += __uint_as_float(pv.z);
        acc[3] += __uint_as_float(pv.w);
        size_t base = ((((size_t)b * 64 + (ho0 + dy)) * 64 + (wo0 + dx)) * 64) + fh * 32 + q;
        *(float4*)(out + base) = make_float4(acc[0], acc[1], acc[2], acc[3]);
    }
}

extern "C" void kernel_launch(void* const* d_in, const int* in_sizes, int n_in,
                              void* d_out, int out_size, void* d_ws, size_t ws_size,
                              hipStream_t stream) {
    const float* x    = (const float*)d_in[0];
    const float* cp   = (const float*)d_in[1];
    const float* wsp  = (const float*)d_in[2];
    const float* wsl  = (const float*)d_in[3];
    const float* bias = (const float*)d_in[4];
    float* out = (float*)d_out;
    uint*  Tsp = (uint*)d_ws;                       // 294912 dwords
    float* Tws = (float*)d_ws + 294912;             // 512*40 = 20480 dwords

    hipLaunchKernelGGL(build_table, dim3(NCIJ), dim3(256), 0, stream,
                       cp, wsp, wsl, Tsp, Tws);
    hipLaunchKernelGGL(kan_conv, dim3(512), dim3(1024), 0, stream,
                       x, Tsp, Tws, bias, out);
}

// Round 12
// 115.762 us; speedup vs baseline: 1.1901x; 1.0540x over previous
//
#include <hip/hip_runtime.h>

// KANvolution: B=4, H=W=66, C=32, F=64, KH=KW=3, Ho=Wo=64, 17 control points.
// Spline = 2-point lerp (hat basis: exactly 2 nonzero weights summing to 1).
//
// d_ws layout:
//   Tsp: uint f16x2 pair (cp_eff[k], cp_eff[k+1]) at dword
//        W(f,cij,k) = (f>>5)*147456 + cij*512 + ((f&31)>>2)*64 + k*4 + (f&3)
//        -> inner ds_read_b128 at dword (cij*512 + q*64 + 4k): 4 dwords = pairs for
//           the wave's 4 filters at lane's k; banks (4k..4k+3): k=0..15 covers each
//           bank exactly twice = b128 2-pass minimum -> conflict-free.
//   Tws: float w_silu in per-(fh,half,chunk,wave) quad-blocks of 36 dwords
//        (stride 40): Q = ((fh*2+h)*16+ch)*8 + wl; Tws[Q*40 + cc*4 + fq]
//        -> wave-uniform s_loads at chunk head = off LDS pipe.

#define NCIJ 288
// LDS dword offsets (1024-thread block, two c-half wave-groups)
#define SPL  0             // 2 x 4608 spline chunk              [0,9216)
#define XPW  9216          // 2 x 1152 xp records (stride-2)     [9216,11520)
#define XSW  11520         // 32 x 100 x-tile                    [11520,14720)
#define TOTW 14720         // 58880 B -> 2 blocks/CU

typedef _Float16 half2_t  __attribute__((ext_vector_type(2)));
typedef __fp16   fp16x2_t __attribute__((ext_vector_type(2)));
union h2u { half2_t h; fp16x2_t f; uint u; };

// ---- build: one block per cij, 256 threads ----
__global__ __launch_bounds__(256)
void build_table(const float* __restrict__ cp, const float* __restrict__ wsp,
                 const float* __restrict__ wsl, uint* __restrict__ Tsp,
                 float* __restrict__ Tws) {
    __shared__ float L[64 * 19];
    __shared__ float Lw[64], Ls[64];
    int cij = blockIdx.x, t = threadIdx.x;
    for (int e = t; e < 64 * 17; e += 256) {
        int f = e / 17, g = e - f * 17;
        L[f * 19 + g] = cp[((size_t)f * NCIJ + cij) * 17 + g];
    }
    if (t < 64) {
        Lw[t] = wsl[t * NCIJ + cij];
        Ls[t] = wsp[t * NCIJ + cij];
    }
    __syncthreads();
    int f = t & 63;
    float s = Ls[f];
    int base = (f >> 5) * (NCIJ * 512) + cij * 512
             + ((f & 31) >> 2) * 64 + (f & 3);
    #pragma unroll
    for (int kk = 0; kk < 4; ++kk) {
        int k = (t >> 6) * 4 + kk;
        h2u cv;
        cv.f = __builtin_amdgcn_cvt_pkrtz(s * L[f * 19 + k], s * L[f * 19 + k + 1]);
        Tsp[base + k * 4] = cv.u;
    }
    if (t < 64) {
        int fh = t >> 5, fl = t & 31, wl = fl >> 2, fq = fl & 3;
        int h = cij / 144, gl = cij - h * 144, ch2 = gl / 9, cc = gl - ch2 * 9;
        int Q = ((fh * 2 + h) * 16 + ch2) * 8 + wl;
        Tws[Q * 40 + cc * 4 + fq] = Lw[t];
    }
}

// ---- main: 512 blocks (256 tiles x 2 fh) x 1024 threads (16 waves) ----
// waves 0-7: channels 0-15 ; waves 8-15: channels 16-31 ; LDS reduction at end.
__global__ __launch_bounds__(1024, 8)
void kan_conv(const float* __restrict__ x, const uint* __restrict__ Tsp,
              const float* __restrict__ Tws, const float* __restrict__ bias,
              float* __restrict__ out) {
    __shared__ uint shm[TOTW];

    int tid = threadIdx.x;
    int lane = tid & 63, w = tid >> 6;
    int half = w >> 3;                     // c-half this wave accumulates
    int wl = w & 7;                        // wave index within half
    int q = wl << 2;                       // f-quarter within the 32-f half
    int ht = tid & 511;                    // thread index within half
    int dy = lane >> 3, dx = lane & 7;
    int bid = blockIdx.x;
    int tile = bid & 255;
    int fh = bid >> 8;
    int b = tile >> 6, ty = (tile >> 3) & 7, tx = tile & 7;
    int ho0 = ty << 3, wo0 = tx << 3;
    int cij0 = half * 144;                 // first cij of this half

    // stage x tile: 10x10 halo x all 32 channels, [c][r*10+col]
    for (int e = tid; e < 3200; e += 1024) {
        int c = e & 31, rc = e >> 5;
        int r = rc / 10, col = rc - r * 10;
        shm[XSW + c * 100 + rc] =
            __float_as_uint(x[(((b * 66) + ho0 + r) * 66 + (wo0 + col)) * 32 + c]);
    }

    float acc[4];
    #pragma unroll
    for (int ff = 0; ff < 4; ++ff)
        acc[ff] = (half == 0) ? bias[fh * 32 + q + ff] : 0.f;

    int hb   = half * 4608;                // this half's spline buffer base
    int wq64 = hb + (wl << 6);             // + wave's quad base

    for (int ch = 0; ch < 16; ++ch) {      // local channel = chunk
        __syncthreads();                   // prev chunk's compute done (covers x tile)

        // w_silu quad-block: wave-uniform -> s_loads into registers, off the LDS pipe.
        int qb = __builtin_amdgcn_readfirstlane(
            ((((fh * 2 + half) * 16 + ch) * 8) + wl) * 40);
        const float* wsq = Tws + qb;
        float4 wv[9];
        #pragma unroll
        for (int cc = 0; cc < 9; ++cc) wv[cc] = *(const float4*)(wsq + cc * 4);

        // stage this half's spline chunk: 1152 uint4, dest contiguous
        {
            int cijc = fh * NCIJ + cij0 + ch * 9;
            const uint4* s1 = (const uint4*)(Tsp + (size_t)cijc * 512);
            uint4* d1 = (uint4*)&shm[hb];
            for (int e = ht; e < 1152; e += 512) d1[e] = s1[e];
        }
        // precompute xp records: 9 taps x 64 pixels, 8B each, stride-2
        {
            int p = ht;
            #pragma unroll 1
            for (int rep = 0; rep < 2; ++rep) {
                if (p < 576) {
                    int ij = p >> 6, px = p & 63;
                    int i = ij / 3, j = ij - i * 3;
                    int pdy = px >> 3, pdx = px & 7;
                    float xv = __uint_as_float(
                        shm[XSW + (half * 16 + ch) * 100 + (pdy + i) * 10 + pdx + j]);
                    float xc = fminf(fmaxf(xv, -1.f), 1.f);
                    float u = fmaf(xc, 8.f, 8.f);
                    int k = (int)u; k = (k > 15) ? 15 : k;
                    float t = u - (float)k;
                    h2u at; at.f = __builtin_amdgcn_cvt_pkrtz(1.f - t, t);
                    float sl = xv * __builtin_amdgcn_rcpf(1.f + __expf(-xv));
                    uint su = (__float_as_uint(sl) & ~15u) | (uint)k;
                    uint2 rec; rec.x = at.u; rec.y = su;
                    *(uint2*)&shm[XPW + half * 1152 + p * 2] = rec;
                }
                p += 512;
            }
        }
        __syncthreads();                   // tab + xp ready

        #pragma unroll
        for (int cc = 0; cc < 9; ++cc) {
            uint2 r = *(const uint2*)&shm[XPW + half * 1152 + lane * 2 + cc * 128];
            uint su = r.y;
            int k2 = (int)(su & 15u);
            float sl = __uint_as_float(su & ~15u);
            // one b128: pairs for this wave's 4 filters at lane's k.
            // banks (4k..4k+3): each bank exactly 2 dwords -> 2-pass minimum.
            uint4 pr = *(const uint4*)&shm[wq64 + cc * 512 + (k2 << 2)];
#if __has_builtin(__builtin_amdgcn_fdot2)
            h2u at; at.u = r.x;
            h2u c0, c1, c2u, c3;
            c0.u = pr.x; c1.u = pr.y; c2u.u = pr.z; c3.u = pr.w;
            acc[0] = __builtin_amdgcn_fdot2(at.h, c0.h, acc[0], false);
            acc[1] = __builtin_amdgcn_fdot2(at.h, c1.h, acc[1], false);
            acc[2] = __builtin_amdgcn_fdot2(at.h, c2u.h, acc[2], false);
            acc[3] = __builtin_amdgcn_fdot2(at.h, c3.h, acc[3], false);
#else
            h2u atv; atv.u = r.x;
            float a0 = (float)atv.h.x, a1 = (float)atv.h.y;
            uint prs[4] = {pr.x, pr.y, pr.z, pr.w};
            #pragma unroll
            for (int ff = 0; ff < 4; ++ff) {
                h2u cv; cv.u = prs[ff];
                acc[ff] = fmaf(a0, (float)cv.h.x, fmaf(a1, (float)cv.h.y, acc[ff]));
            }
#endif
            acc[0] = fmaf(sl, wv[cc].x, acc[0]);
            acc[1] = fmaf(sl, wv[cc].y, acc[1]);
            acc[2] = fmaf(sl, wv[cc].z, acc[2]);
            acc[3] = fmaf(sl, wv[cc].w, acc[3]);
        }
    }

    // block-internal reduction: half 1 writes partials, half 0 adds + stores
    __syncthreads();
    if (half == 1) {
        uint4 pv;
        pv.x = __float_as_uint(acc[0]); pv.y = __float_as_uint(acc[1]);
        pv.z = __float_as_uint(acc[2]); pv.w = __float_as_uint(acc[3]);
        *(uint4*)&shm[wl * 256 + lane * 4] = pv;
    }
    __syncthreads();
    if (half == 0) {
        uint4 pv = *(const uint4*)&shm[wl * 256 + lane * 4];
        acc[0] += __uint_as_float(pv.x);
        acc[1] += __uint_as_float(pv.y);
        acc[2] += __uint_as_float(pv.z);
        acc[3] += __uint_as_float(pv.w);
        size_t base = ((((size_t)b * 64 + (ho0 + dy)) * 64 + (wo0 + dx)) * 64) + fh * 32 + q;
        *(float4*)(out + base) = make_float4(acc[0], acc[1], acc[2], acc[3]);
    }
}

extern "C" void kernel_launch(void* const* d_in, const int* in_sizes, int n_in,
                              void* d_out, int out_size, void* d_ws, size_t ws_size,
                              hipStream_t stream) {
    const float* x    = (const float*)d_in[0];
    const float* cp   = (const float*)d_in[1];
    const float* wsp  = (const float*)d_in[2];
    const float* wsl  = (const float*)d_in[3];
    const float* bias = (const float*)d_in[4];
    float* out = (float*)d_out;
    uint*  Tsp = (uint*)d_ws;                       // 294912 dwords
    float* Tws = (float*)d_ws + 294912;             // 512*40 = 20480 dwords

    hipLaunchKernelGGL(build_table, dim3(NCIJ), dim3(256), 0, stream,
                       cp, wsp, wsl, Tsp, Tws);
    hipLaunchKernelGGL(kan_conv, dim3(512), dim3(1024), 0, stream,
                       x, Tsp, Tws, bias, out);
}